// Round 1
// baseline (89.072 us; speedup 1.0000x reference)
//
#include <hip/hip_runtime.h>
#include <math.h>

#define TROWS 16
#define FFEAT 129
#define DD    64

__device__ __forceinline__ float lane_bcast(float v, int k) {
    return __uint_as_float(__builtin_amdgcn_readlane(__float_as_uint(v), k));
}

__global__ __launch_bounds__(256, 8) void dtw_tracker_kernel(
    const float* __restrict__ fh,
    const float* __restrict__ W1,
    const float* __restrict__ b1,
    const float* __restrict__ gamma,
    const float* __restrict__ beta,
    const float* __restrict__ W2,
    const float* __restrict__ b2,
    float* __restrict__ out,
    int nB)
{
    __shared__ float sW1[DD * DD];

    const int tid  = threadIdx.x;
    const int lane = tid & 63;
    const int wib  = tid >> 6;

    // Stage W1 (64x64 f32 = 16 KB) into LDS, vectorized float4.
    for (int i = tid * 4; i < DD * DD; i += 256 * 4) {
        *reinterpret_cast<float4*>(&sW1[i]) =
            *reinterpret_cast<const float4*>(&W1[i]);
    }
    __syncthreads();

    // Per-lane constants (hoisted out of the batch loop; L1/L2-cached).
    const float b1j = b1[lane];
    const float gj  = gamma[lane];
    const float bj  = beta[lane];
    const float w2j = W2[lane];
    const float b2s = b2[0];

    const int nWaves = gridDim.x * 4;
    for (int b = blockIdx.x * 4 + wib; b < nB; b += nWaves) {
        // Load freq_history[b, 13:16, lane]  (cutoff = 64 == wave width)
        const float* base = fh + (size_t)b * (TROWS * FFEAT) + 13 * FFEAT + lane;
        const float x13 = base[0];
        const float x14 = base[FFEAT];
        const float x15 = base[2 * FFEAT];

        // hfm = clip(|x|, 1e-5, 10)
        const float a13 = fminf(fmaxf(fabsf(x13), 1e-5f), 10.0f);
        const float a14 = fminf(fmaxf(fabsf(x14), 1e-5f), 10.0f);
        const float a15 = fminf(fmaxf(fabsf(x15), 1e-5f), 10.0f);

        // mean/std (ddof=1) over the 3x64 = 192 values (wave reduction).
        float s  = a13 + a14 + a15;
        float sq = a13 * a13 + a14 * a14 + a15 * a15;
        #pragma unroll
        for (int m = 32; m >= 1; m >>= 1) {
            s  += __shfl_xor(s,  m, 64);
            sq += __shfl_xor(sq, m, 64);
        }
        const float mean = s * (1.0f / 192.0f);
        float var = (sq - s * s * (1.0f / 192.0f)) * (1.0f / 191.0f);
        var = fmaxf(var, 0.0f);
        const float stdv = sqrtf(var) + 1e-5f;

        // latest = clip((a15 - mean)/std, -3, 3)
        const float latest = fminf(fmaxf((a15 - mean) / stdv, -3.0f), 3.0f);

        // h[lane] = b1[lane] + sum_k latest[k] * W1[k, lane]
        // broadcast latest[k] via v_readlane (constant k, fully unrolled)
        float h = b1j;
        #pragma unroll
        for (int k = 0; k < DD; ++k) {
            h = fmaf(lane_bcast(latest, k), sW1[k * DD + lane], h);
        }

        // LayerNorm over the 64 features (biased var), gamma/beta.
        float hs = h, hsq = h * h;
        #pragma unroll
        for (int m = 32; m >= 1; m >>= 1) {
            hs  += __shfl_xor(hs,  m, 64);
            hsq += __shfl_xor(hsq, m, 64);
        }
        const float mu   = hs * (1.0f / 64.0f);
        float varh = hsq * (1.0f / 64.0f) - mu * mu;
        varh = fmaxf(varh, 0.0f);
        const float rstd = rsqrtf(varh + 1e-5f);
        const float hn = (h - mu) * rstd * gj + bj;

        // exact GELU: 0.5*x*(1+erf(x/sqrt(2)))
        const float g = 0.5f * hn * (1.0f + erff(hn * 0.70710678118654752440f));

        // score = sigmoid(g . W2 + b2); dist from RAW rows t13/t15.
        const float d0 = x13 - x15;
        float sc = g * w2j;
        float dd = d0 * d0;
        #pragma unroll
        for (int m = 32; m >= 1; m >>= 1) {
            sc += __shfl_xor(sc, m, 64);
            dd += __shfl_xor(dd, m, 64);
        }
        const float rep = 1.0f / (1.0f + expf(-(sc + b2s)));
        const float sim = expf(-sqrtf(dd) * (1.0f / 256.0f));

        if (lane == 0) {
            out[b]      = rep;
            out[nB + b] = sim;
        }
    }
}

extern "C" void kernel_launch(void* const* d_in, const int* in_sizes, int n_in,
                              void* d_out, int out_size, void* d_ws, size_t ws_size,
                              hipStream_t stream) {
    const float* fh    = (const float*)d_in[0];
    const float* W1    = (const float*)d_in[1];
    const float* b1    = (const float*)d_in[2];
    const float* gamma = (const float*)d_in[3];
    const float* beta  = (const float*)d_in[4];
    const float* W2    = (const float*)d_in[5];
    const float* b2    = (const float*)d_in[6];
    float* out = (float*)d_out;

    const int nB = in_sizes[0] / (TROWS * FFEAT);   // 65536

    // 2048 blocks x 256 threads = 8192 waves; 8 batches per wave (grid-stride).
    dtw_tracker_kernel<<<2048, 256, 0, stream>>>(fh, W1, b1, gamma, beta, W2, b2,
                                                 out, nB);
}

// Round 2
// 45.387 us; speedup vs baseline: 1.9625x; 1.9625x over previous
//
#include <hip/hip_runtime.h>
#include <math.h>

#define TROWS 16
#define FFEAT 129
#define DD    64

__device__ __forceinline__ float lane_bcast(float v, int k) {
    return __uint_as_float(__builtin_amdgcn_readlane(__float_as_uint(v), k));
}

__global__ __launch_bounds__(256, 4) void dtw_tracker_kernel(
    const float* __restrict__ fh,
    const float* __restrict__ W1,
    const float* __restrict__ b1,
    const float* __restrict__ gamma,
    const float* __restrict__ beta,
    const float* __restrict__ W2,
    const float* __restrict__ b2,
    float* __restrict__ out,
    int nB)
{
    const int tid  = threadIdx.x;
    const int lane = tid & 63;
    const int wib  = tid >> 6;

    // Each lane holds column `lane` of W1 in 64 VGPRs.
    // For fixed k, lanes read consecutive addresses -> fully coalesced;
    // W1 is 16 KB so it is L2-resident after the first blocks touch it.
    float w1c[DD];
    #pragma unroll
    for (int k = 0; k < DD; ++k) w1c[k] = W1[k * DD + lane];

    // Per-lane constants.
    const float b1j = b1[lane];
    const float gj  = gamma[lane];
    const float bj  = beta[lane];
    const float w2j = W2[lane];
    const float b2s = b2[0];

    const int stride = gridDim.x * 4;
    int b = blockIdx.x * 4 + wib;
    if (b >= nB) return;

    // Prime the software pipeline: load batch b's three rows.
    const float* base = fh + (size_t)b * (TROWS * FFEAT) + 13 * FFEAT + lane;
    float x13 = base[0];
    float x14 = base[FFEAT];
    float x15 = base[2 * FFEAT];

    while (b < nB) {
        // ---- prefetch next batch's rows (overlaps with compute below) ----
        const int bn = b + stride;
        const int bl = (bn < nB) ? bn : b;            // clamp: always load in-bounds
        const float* nbase = fh + (size_t)bl * (TROWS * FFEAT) + 13 * FFEAT + lane;
        const float n13 = nbase[0];
        const float n14 = nbase[FFEAT];
        const float n15 = nbase[2 * FFEAT];

        // ---- hfm = clip(|x|, 1e-5, 10) ----
        const float a13 = fminf(fmaxf(fabsf(x13), 1e-5f), 10.0f);
        const float a14 = fminf(fmaxf(fabsf(x14), 1e-5f), 10.0f);
        const float a15 = fminf(fmaxf(fabsf(x15), 1e-5f), 10.0f);

        // mean/std (ddof=1) over 3x64 = 192 values.
        float s  = a13 + a14 + a15;
        float sq = a13 * a13 + a14 * a14 + a15 * a15;
        #pragma unroll
        for (int m = 32; m >= 1; m >>= 1) {
            s  += __shfl_xor(s,  m, 64);
            sq += __shfl_xor(sq, m, 64);
        }
        const float mean = s * (1.0f / 192.0f);
        float var = (sq - s * s * (1.0f / 192.0f)) * (1.0f / 191.0f);
        var = fmaxf(var, 0.0f);
        const float stdv = sqrtf(var) + 1e-5f;

        const float latest = fminf(fmaxf((a15 - mean) / stdv, -3.0f), 3.0f);

        // ---- h = latest @ W1 + b1, 4-way split accumulators ----
        float h0 = 0.0f, h1 = 0.0f, h2 = 0.0f, h3 = 0.0f;
        #pragma unroll
        for (int k = 0; k < DD; k += 4) {
            h0 = fmaf(lane_bcast(latest, k + 0), w1c[k + 0], h0);
            h1 = fmaf(lane_bcast(latest, k + 1), w1c[k + 1], h1);
            h2 = fmaf(lane_bcast(latest, k + 2), w1c[k + 2], h2);
            h3 = fmaf(lane_bcast(latest, k + 3), w1c[k + 3], h3);
        }
        const float h = b1j + ((h0 + h1) + (h2 + h3));

        // ---- LayerNorm over 64 features ----
        float hs = h, hsq = h * h;
        #pragma unroll
        for (int m = 32; m >= 1; m >>= 1) {
            hs  += __shfl_xor(hs,  m, 64);
            hsq += __shfl_xor(hsq, m, 64);
        }
        const float mu   = hs * (1.0f / 64.0f);
        float varh = hsq * (1.0f / 64.0f) - mu * mu;
        varh = fmaxf(varh, 0.0f);
        const float rstd = rsqrtf(varh + 1e-5f);
        const float hn = (h - mu) * rstd * gj + bj;

        // exact GELU
        const float g = 0.5f * hn * (1.0f + erff(hn * 0.70710678118654752440f));

        // ---- score + dtw distance (raw rows!) ----
        const float d0 = x13 - x15;
        float sc = g * w2j;
        float dd = d0 * d0;
        #pragma unroll
        for (int m = 32; m >= 1; m >>= 1) {
            sc += __shfl_xor(sc, m, 64);
            dd += __shfl_xor(dd, m, 64);
        }

        if (lane == 0) out[b] = 1.0f / (1.0f + expf(-(sc + b2s)));
        if (lane == 1) out[nB + b] = expf(-sqrtf(dd) * (1.0f / 256.0f));

        // rotate pipeline
        b = bn;
        x13 = n13; x14 = n14; x15 = n15;
    }
}

extern "C" void kernel_launch(void* const* d_in, const int* in_sizes, int n_in,
                              void* d_out, int out_size, void* d_ws, size_t ws_size,
                              hipStream_t stream) {
    const float* fh    = (const float*)d_in[0];
    const float* W1    = (const float*)d_in[1];
    const float* b1    = (const float*)d_in[2];
    const float* gamma = (const float*)d_in[3];
    const float* beta  = (const float*)d_in[4];
    const float* W2    = (const float*)d_in[5];
    const float* b2    = (const float*)d_in[6];
    float* out = (float*)d_out;

    const int nB = in_sizes[0] / (TROWS * FFEAT);   // 65536

    // 2048 blocks x 4 waves = 8192 waves; 8 batches per wave (grid-stride).
    dtw_tracker_kernel<<<2048, 256, 0, stream>>>(fh, W1, b1, gamma, beta, W2, b2,
                                                 out, nB);
}

// Round 3
// 40.447 us; speedup vs baseline: 2.2022x; 1.1221x over previous
//
#include <hip/hip_runtime.h>
#include <math.h>

#define TROWS 16
#define FFEAT 129
#define DD    64

__device__ __forceinline__ float lane_bcast(float v, int k) {
    return __uint_as_float(__builtin_amdgcn_readlane(__float_as_uint(v), k));
}

// x + dpp_mov(x, ctrl); invalid source lanes contribute 0.
#define DPP_ADD(x, ctrl)                                                     \
    (x) += __int_as_float(__builtin_amdgcn_update_dpp(                       \
        0, __float_as_int(x), (ctrl), 0xf, 0xf, true))

// Full 64-lane sum -> wave-uniform scalar (classic gfx9 DPP ladder):
// row_shr:1,2,4,8 builds row-of-16 inclusive sums (lane15/31/47/63 hold row
// totals), row_bcast:15 then row_bcast:31 fold rows; lane63 = grand total.
__device__ __forceinline__ float wave_sum64(float x) {
    DPP_ADD(x, 0x111);   // row_shr:1
    DPP_ADD(x, 0x112);   // row_shr:2
    DPP_ADD(x, 0x114);   // row_shr:4
    DPP_ADD(x, 0x118);   // row_shr:8
    DPP_ADD(x, 0x142);   // row_bcast:15
    DPP_ADD(x, 0x143);   // row_bcast:31
    return lane_bcast(x, 63);
}

__global__ __launch_bounds__(256, 4) void dtw_tracker_kernel(
    const float* __restrict__ fh,
    const float* __restrict__ W1,
    const float* __restrict__ b1,
    const float* __restrict__ gamma,
    const float* __restrict__ beta,
    const float* __restrict__ W2,
    const float* __restrict__ b2,
    float* __restrict__ out,
    int nB)
{
    const int tid  = threadIdx.x;
    const int lane = tid & 63;
    const int wib  = tid >> 6;

    // Lane holds column `lane` of W1 in 64 VGPRs (coalesced load, L2-hot).
    float w1c[DD];
    #pragma unroll
    for (int k = 0; k < DD; ++k) w1c[k] = W1[k * DD + lane];

    const float b1j = b1[lane];
    const float gj  = gamma[lane];
    const float bj  = beta[lane];
    const float w2j = W2[lane];
    const float b2s = b2[0];

    const int stride = gridDim.x * 4;
    int b = blockIdx.x * 4 + wib;
    if (b >= nB) return;

    // Prime software pipeline.
    const float* base = fh + (size_t)b * (TROWS * FFEAT) + 13 * FFEAT + lane;
    float x13 = base[0];
    float x14 = base[FFEAT];
    float x15 = base[2 * FFEAT];

    while (b < nB) {
        // ---- prefetch next batch (overlaps compute) ----
        const int bn = b + stride;
        const int bl = (bn < nB) ? bn : b;
        const float* nbase = fh + (size_t)bl * (TROWS * FFEAT) + 13 * FFEAT + lane;
        const float n13 = nbase[0];
        const float n14 = nbase[FFEAT];
        const float n15 = nbase[2 * FFEAT];

        // ---- hfm = clip(|x|, 1e-5, 10) ----
        const float a13 = fminf(fmaxf(fabsf(x13), 1e-5f), 10.0f);
        const float a14 = fminf(fmaxf(fabsf(x14), 1e-5f), 10.0f);
        const float a15 = fminf(fmaxf(fabsf(x15), 1e-5f), 10.0f);

        // mean/std (ddof=1) over 3x64 values — two DPP ladders (pure VALU).
        float s  = a13 + a14 + a15;
        float sq = fmaf(a13, a13, fmaf(a14, a14, a15 * a15));
        const float S  = wave_sum64(s);
        const float SQ = wave_sum64(sq);
        const float mean = S * (1.0f / 192.0f);
        float var = (SQ - S * S * (1.0f / 192.0f)) * (1.0f / 191.0f);
        var = fmaxf(var, 0.0f);
        const float stdv = sqrtf(var) + 1e-5f;

        const float latest = fminf(fmaxf((a15 - mean) / stdv, -3.0f), 3.0f);

        // ---- h = latest @ W1 + b1 (readlane broadcast, 4 accumulators) ----
        float h0 = 0.0f, h1 = 0.0f, h2 = 0.0f, h3 = 0.0f;
        #pragma unroll
        for (int k = 0; k < DD; k += 4) {
            h0 = fmaf(lane_bcast(latest, k + 0), w1c[k + 0], h0);
            h1 = fmaf(lane_bcast(latest, k + 1), w1c[k + 1], h1);
            h2 = fmaf(lane_bcast(latest, k + 2), w1c[k + 2], h2);
            h3 = fmaf(lane_bcast(latest, k + 3), w1c[k + 3], h3);
        }
        const float h = b1j + ((h0 + h1) + (h2 + h3));

        // ---- LayerNorm over 64 features ----
        const float HS  = wave_sum64(h);
        const float HSQ = wave_sum64(h * h);
        const float mu   = HS * (1.0f / 64.0f);
        float varh = HSQ * (1.0f / 64.0f) - mu * mu;
        varh = fmaxf(varh, 0.0f);
        const float rstd = rsqrtf(varh + 1e-5f);
        const float hn = (h - mu) * rstd * gj + bj;

        // exact GELU
        const float g = 0.5f * hn * (1.0f + erff(hn * 0.70710678118654752440f));

        // ---- score + dtw distance (raw rows!) ----
        const float d0 = x13 - x15;
        const float SC = wave_sum64(g * w2j);
        const float DDist = wave_sum64(d0 * d0);

        const float rep = 1.0f / (1.0f + __expf(-(SC + b2s)));
        const float sim = __expf(-sqrtf(DDist) * (1.0f / 256.0f));
        if (lane == 0) {
            out[b]      = rep;
            out[nB + b] = sim;
        }

        // rotate pipeline
        b = bn;
        x13 = n13; x14 = n14; x15 = n15;
    }
}

extern "C" void kernel_launch(void* const* d_in, const int* in_sizes, int n_in,
                              void* d_out, int out_size, void* d_ws, size_t ws_size,
                              hipStream_t stream) {
    const float* fh    = (const float*)d_in[0];
    const float* W1    = (const float*)d_in[1];
    const float* b1    = (const float*)d_in[2];
    const float* gamma = (const float*)d_in[3];
    const float* beta  = (const float*)d_in[4];
    const float* W2    = (const float*)d_in[5];
    const float* b2    = (const float*)d_in[6];
    float* out = (float*)d_out;

    const int nB = in_sizes[0] / (TROWS * FFEAT);   // 65536

    dtw_tracker_kernel<<<2048, 256, 0, stream>>>(fh, W1, b1, gamma, beta, W2, b2,
                                                 out, nB);
}